// Round 11
// baseline (233.131 us; speedup 1.0000x reference)
//
#include <hip/hip_runtime.h>
#include <hip/hip_bf16.h>

#define N_NODES 100000
#define N_EDGES 1000000
#define DIM 64
#define NORM_INV 0.01f
#define LN_EPS 1e-5f
#define N_TILES 6250          // N_NODES/16
#define PROJ_BLOCKS 1563      // ceil(6250/4)
#define N_BUCKETS 1563        // ceil(100000/64), 64 rows per bucket
#define AGG_C0 782            // agg chunk 0 blocks
#define AGG_C1 781            // agg chunk 1 blocks
#define HB_PK 784             // packed-int count: 1568 u16 bins (>=1564)
#define SC_EDGES 4096         // edges per scatter slice
#define SC_BLOCKS 245         // ceil(1e6/4096)
#define OFS_STRIDE 1568       // u16 per ofsT row (1564 used, padded)
#define L2E 1.4426950408889634f
#define LN2 0.6931471805599453f
#define CAP 1280              // LDS record capacity/bucket

typedef __attribute__((ext_vector_type(8))) short short8;
typedef __attribute__((ext_vector_type(4))) float f32x4;

__device__ __forceinline__ unsigned short f2bf(float f) {
    union { float f; unsigned u; } x; x.f = f;
    unsigned r = x.u + 0x7FFFu + ((x.u >> 16) & 1u);
    return (unsigned short)(r >> 16);
}
__device__ __forceinline__ float bf2f(unsigned short s) {
    union { unsigned u; float f; } x; x.u = ((unsigned)s) << 16; return x.f;
}

// ---------------------------------------------------------------------------
// proj_scatter fat kernel (round-8 structure; best-known producer config).
// blocks [0, SC_BLOCKS): fixed-slice scatter. 1563 bins (64-row buckets),
//   two 16-bit counters packed per LDS int (counts <= 4096, no carry).
//   srec.x = col | lrow<<24 (lrow = row & 63). ofsT stored as u16.
// blocks [SC_BLOCKS, +PROJ_BLOCKS): MFMA projection, 1 tile/wave; weight
//   fragments built in-block into LDS (32 KB), whi/wlo region reused for lw.
//   xv written as ONE fused uint4 per (r, lane) — no split half-line stores.
// ---------------------------------------------------------------------------
__global__ __launch_bounds__(256) void proj_scatter(
    const float* __restrict__ h, const float* __restrict__ bl,
    const float* __restrict__ W, const float* __restrict__ att_W1,
    const int* __restrict__ edges, const float* __restrict__ dist,
    const float* __restrict__ emask,
    uint2* __restrict__ srec, unsigned short* __restrict__ ofsT,
    unsigned short* __restrict__ xv, unsigned short* __restrict__ u_bf) {
    __shared__ __align__(16) char pool[39168];
    __shared__ int wsum[4];

    if (blockIdx.x < SC_BLOCKS) {
        // ------------------- scatter personality -------------------
        int* lh = (int*)pool;                       // [HB_PK] packed counts
        int* lofsP = (int*)pool + HB_PK;            // [HB_PK] packed offsets
        uint2* lsort = (uint2*)(pool + 6272);       // [SC_EDGES]
        const int blk = blockIdx.x;
        const int tid = threadIdx.x;
        const int lane = tid & 63;
        const int w = tid >> 6;
        for (int i = tid; i < HB_PK; i += 256) lh[i] = 0;
        __syncthreads();

        const int eb = blk * SC_EDGES;
        const int total = min(SC_EDGES, N_EDGES - eb);

        // Phase A: load 16 edges/thread, histogram with rank capture.
        int rows[16], rank[16];
        uint2 recs[16];
        const int e0 = eb + tid * 16;
#pragma unroll
        for (int g = 0; g < 4; ++g) {
            const int e = e0 + g * 4;
            if (e + 4 <= N_EDGES) {
                const int4 rr = *(const int4*)(edges + e);
                const int4 cc = *(const int4*)(edges + N_EDGES + e);
                const float4 dd = *(const float4*)(dist + e);
                const float4 mm = *(const float4*)(emask + e);
                rows[g*4+0] = rr.x; rows[g*4+1] = rr.y; rows[g*4+2] = rr.z; rows[g*4+3] = rr.w;
                const int c4[4] = {cc.x, cc.y, cc.z, cc.w};
                const float d4[4] = {dd.x, dd.y, dd.z, dd.w};
                const float m4[4] = {mm.x, mm.y, mm.z, mm.w};
#pragma unroll
                for (int i = 0; i < 4; ++i) {
                    const int ii = g * 4 + i;
                    recs[ii].x = (unsigned)c4[i] | ((unsigned)(rows[ii] & 63) << 24);
                    recs[ii].y = (unsigned)f2bf(d4[i]) |
                                 ((unsigned)f2bf(m4[i] * NORM_INV) << 16);
                    const int bk = rows[ii] >> 6;
                    const int sh = (bk & 1) << 4;
                    rank[ii] = (atomicAdd(&lh[bk >> 1], 1 << sh) >> sh) & 0xffff;
                }
            } else {
#pragma unroll
                for (int i = 0; i < 4; ++i) {
                    const int ii = g * 4 + i;
                    const int ee = e + i;
                    if (ee < N_EDGES) {
                        rows[ii] = edges[ee];
                        recs[ii].x = (unsigned)edges[N_EDGES + ee] |
                                     ((unsigned)(rows[ii] & 63) << 24);
                        recs[ii].y = (unsigned)f2bf(dist[ee]) |
                                     ((unsigned)f2bf(emask[ee] * NORM_INV) << 16);
                        const int bk = rows[ii] >> 6;
                        const int sh = (bk & 1) << 4;
                        rank[ii] = (atomicAdd(&lh[bk >> 1], 1 << sh) >> sh) & 0xffff;
                    } else {
                        rows[ii] = -1;
                    }
                }
            }
        }
        __syncthreads();

        // Phase B: 8-bins/thread exclusive scan over 1568 packed bins.
        const int t4 = tid * 4;
        int li[4];
#pragma unroll
        for (int g = 0; g < 4; ++g) li[g] = (t4 + g < HB_PK) ? lh[t4 + g] : 0;
        int cs[8];
#pragma unroll
        for (int g = 0; g < 4; ++g) {
            cs[2*g]   = li[g] & 0xffff;
            cs[2*g+1] = (li[g] >> 16) & 0xffff;
        }
        int S = 0;
#pragma unroll
        for (int k = 0; k < 8; ++k) S += cs[k];
        int sc = S;
#pragma unroll
        for (int off = 1; off < 64; off <<= 1) {
            int u = __shfl_up(sc, off);
            if (lane >= off) sc += u;
        }
        if (lane == 63) wsum[w] = sc;
        __syncthreads();
        int wbase = 0;
        if (w > 0) wbase = wsum[0];
        if (w > 1) wbase += wsum[1];
        if (w > 2) wbase += wsum[2];
        int run = sc - S + wbase;
#pragma unroll
        for (int g = 0; g < 4; ++g) {
            const int lo = run; run += cs[2*g];
            const int hi = run; run += cs[2*g+1];
            if (t4 + g < HB_PK) lofsP[t4 + g] = (unsigned)lo | ((unsigned)hi << 16);
        }
        __syncthreads();

        // Phase C: place into LDS sorted by bucket.
#pragma unroll
        for (int i = 0; i < 16; ++i) {
            if (rows[i] >= 0) {
                const int bk = rows[i] >> 6;
                const int base = (lofsP[bk >> 1] >> ((bk & 1) << 4)) & 0xffff;
                lsort[base + rank[i]] = recs[i];
            }
        }
        __syncthreads();

        // Phase D: fully-coalesced slice write-out + u16 ofsT row.
        for (int s = tid; s < total; s += 256)
            srec[(size_t)blk * SC_EDGES + s] = lsort[s];
        for (int b = tid; b < 1564; b += 256)
            ofsT[blk * OFS_STRIDE + b] =
                (unsigned short)((lofsP[b >> 1] >> ((b & 1) << 4)) & 0xffff);
        return;
    }

    // ------------------- projection personality -------------------
    const int tid = threadIdx.x;
    const int lane = tid & 63;
    const int wv = tid >> 6;
    const int c = lane & 15, q = lane >> 4;

    // In-block fragment build: W hi/lo split + att_W1 a/b fragments -> LDS.
    {
        short8* Lwhi_w = (short8*)pool;
        short8* Lwlo_w = Lwhi_w + 512;
        short8* Lwa_w  = Lwhi_w + 1024;
        short8* Lwb_w  = Lwhi_w + 1536;
        const int nt_b = tid >> 6;
        const int n_b = nt_b * 16 + c;
#pragma unroll
        for (int ks = 0; ks < 2; ++ks) {
            const int k0 = ks * 32 + q * 8;
            short8 hi8, lo8, a8, b8;
#pragma unroll
            for (int jj = 0; jj < 8; ++jj) {
                float w = W[n_b * 64 + k0 + jj];
                unsigned short hh = f2bf(w);
                hi8[jj] = (short)hh;
                lo8[jj] = (short)f2bf(w - bf2f(hh));
                a8[jj] = (short)f2bf(att_W1[n_b * 129 + k0 + jj]);
                b8[jj] = (short)f2bf(att_W1[n_b * 129 + 64 + k0 + jj]);
            }
            const int idx = (nt_b * 2 + ks) * 64 + lane;
            Lwhi_w[idx] = hi8; Lwlo_w[idx] = lo8; Lwa_w[idx] = a8; Lwb_w[idx] = b8;
        }
    }
    __syncthreads();
    const short8* Lwhi = (const short8*)pool;
    const short8* Lwlo = Lwhi + 512;
    const short8* Lwa  = Lwhi + 1024;
    const short8* Lwb  = Lwhi + 1536;

    const int tile = (blockIdx.x - SC_BLOCKS) * 4 + wv;
    const bool valid = (tile < N_TILES);
    const int n0 = valid ? tile * 16 : 0;

    float bias[4];
#pragma unroll
    for (int nt = 0; nt < 4; ++nt) bias[nt] = bl[nt * 16 + c];

    short8 Ahi[2], Alo[2];
#pragma unroll
    for (int ks = 0; ks < 2; ++ks) {
        const float* hp = h + (size_t)(n0 + c) * 64 + ks * 32 + q * 8;
        f32x4 p0 = *(const f32x4*)hp;
        f32x4 p1 = *(const f32x4*)(hp + 4);
        short8 hi8, lo8;
#pragma unroll
        for (int jj = 0; jj < 4; ++jj) {
            unsigned short hh = f2bf(p0[jj]);
            hi8[jj] = (short)hh; lo8[jj] = (short)f2bf(p0[jj] - bf2f(hh));
            unsigned short h2 = f2bf(p1[jj]);
            hi8[4 + jj] = (short)h2; lo8[4 + jj] = (short)f2bf(p1[jj] - bf2f(h2));
        }
        Ahi[ks] = hi8; Alo[ks] = lo8;
    }

    f32x4 xacc[4] = {{0,0,0,0},{0,0,0,0},{0,0,0,0},{0,0,0,0}};
#pragma unroll
    for (int ks = 0; ks < 2; ++ks)
#pragma unroll
        for (int nt = 0; nt < 4; ++nt) {
            const short8 fhi = Lwhi[(nt * 2 + ks) * 64 + lane];
            const short8 flo = Lwlo[(nt * 2 + ks) * 64 + lane];
            xacc[nt] = __builtin_amdgcn_mfma_f32_16x16x32_bf16(Ahi[ks], fhi, xacc[nt], 0, 0, 0);
            xacc[nt] = __builtin_amdgcn_mfma_f32_16x16x32_bf16(Ahi[ks], flo, xacc[nt], 0, 0, 0);
            xacc[nt] = __builtin_amdgcn_mfma_f32_16x16x32_bf16(Alo[ks], fhi, xacc[nt], 0, 0, 0);
        }

    // whi/wlo fragments are dead from here; reuse [0:9216) of pool for lw.
    __syncthreads();

    unsigned short* lw = (unsigned short*)pool + wv * (16 * 72);
    uint2 xpk[4];                    // packed x per r, held until fused store
#pragma unroll
    for (int r = 0; r < 4; ++r) {
        unsigned short xb[4];
#pragma unroll
        for (int nt = 0; nt < 4; ++nt) {
            unsigned short v16 = f2bf(xacc[nt][r] + bias[nt]);
            xb[nt] = v16;
            lw[(q * 4 + r) * 72 + nt * 16 + c] = v16;
        }
        xpk[r].x = (unsigned)xb[0] | ((unsigned)xb[1] << 16);
        xpk[r].y = (unsigned)xb[2] | ((unsigned)xb[3] << 16);
    }

    short8 Ax[2];
#pragma unroll
    for (int ks = 0; ks < 2; ++ks)
        Ax[ks] = *(const short8*)&lw[c * 72 + ks * 32 + q * 8];

    f32x4 uacc[4] = {{0,0,0,0},{0,0,0,0},{0,0,0,0},{0,0,0,0}};
    f32x4 vacc[4] = {{0,0,0,0},{0,0,0,0},{0,0,0,0},{0,0,0,0}};
#pragma unroll
    for (int ks = 0; ks < 2; ++ks)
#pragma unroll
        for (int nt = 0; nt < 4; ++nt) {
            const short8 fa = Lwa[(nt * 2 + ks) * 64 + lane];
            const short8 fb = Lwb[(nt * 2 + ks) * 64 + lane];
            uacc[nt] = __builtin_amdgcn_mfma_f32_16x16x32_bf16(Ax[ks], fa, uacc[nt], 0, 0, 0);
            vacc[nt] = __builtin_amdgcn_mfma_f32_16x16x32_bf16(Ax[ks], fb, vacc[nt], 0, 0, 0);
        }
    if (valid) {
#pragma unroll
        for (int r = 0; r < 4; ++r) {
            const int node = n0 + q * 4 + r;
            uint2 pu;
            pu.x = (unsigned)f2bf(uacc[0][r] * L2E) | ((unsigned)f2bf(uacc[1][r] * L2E) << 16);
            pu.y = (unsigned)f2bf(uacc[2][r] * L2E) | ((unsigned)f2bf(uacc[3][r] * L2E) << 16);
            *(uint2*)(u_bf + (size_t)node * 64 + c * 4) = pu;
            uint4 pk;
            pk.x = xpk[r].x;
            pk.y = xpk[r].y;
            pk.z = (unsigned)f2bf(vacc[0][r] * L2E) | ((unsigned)f2bf(vacc[1][r] * L2E) << 16);
            pk.w = (unsigned)f2bf(vacc[2][r] * L2E) | ((unsigned)f2bf(vacc[3][r] * L2E) << 16);
            *(uint4*)(xv + (size_t)node * 128 + c * 8) = pk;
        }
    }
}

// ---------------------------------------------------------------------------
// agg_fused: one block (256 thr, 4 waves) per 64-row bucket. Round-8 body;
// grid is split into 2 chunk launches (bbase param) so each dispatch runs
// ~41 us — forcing proj_scatter into the rocprof top-5 for the first time.
// ---------------------------------------------------------------------------
__global__ __launch_bounds__(256, 8) void agg_fused(
    const uint2* __restrict__ srec, const unsigned short* __restrict__ ofsT,
    const unsigned short* __restrict__ xv, const unsigned short* __restrict__ u_bf,
    const float* __restrict__ att_W1, const float* __restrict__ att_b1,
    const float* __restrict__ att_W2, const float* __restrict__ att_b2,
    const float* __restrict__ ln_g, const float* __restrict__ ln_b,
    float* __restrict__ out, const int bbase) {
    __shared__ __align__(16) uint2 lrecs[CAP + 16];
    __shared__ float4 ltab[64];
    __shared__ int hist[64];
    __shared__ int rst[65];
    __shared__ int cur[64];
    __shared__ int sst[256];
    __shared__ int dbase[257];
    __shared__ int wsum4[4];

    const int b = bbase + blockIdx.x;
    const int tid = threadIdx.x;
    const int lane = tid & 63;
    const int wv = tid >> 6;

    if (tid < 64) hist[tid] = 0;
    if (tid >= 192) {
        const int f = tid - 192;
        ltab[f] = make_float4(att_W2[f] * LN2, att_W1[f * 129 + 128] * L2E,
                              att_b1[f] * L2E, 0.f);
    }

    // Phase 0: extent lengths + exclusive scan over 256 threads.
    int stv = 0, len = 0, sc0 = 0;
    {
        if (tid < SC_BLOCKS) {
            stv = (int)ofsT[tid * OFS_STRIDE + b];
            len = (int)ofsT[tid * OFS_STRIDE + b + 1] - stv;
        }
        sst[tid] = stv;
        sc0 = len;
#pragma unroll
        for (int off = 1; off < 64; off <<= 1) {
            int u = __shfl_up(sc0, off);
            if (lane >= off) sc0 += u;
        }
        if (lane == 63) wsum4[wv] = sc0;
    }
    __syncthreads();
    {
        int wbase = 0;
        if (wv > 0) wbase = wsum4[0];
        if (wv > 1) wbase += wsum4[1];
        if (wv > 2) wbase += wsum4[2];
        dbase[tid] = wbase + sc0 - len;
        if (tid == 255) dbase[256] = wbase + sc0;
    }
    __syncthreads();
    const int cnt = dbase[245];

    // Phase 1: distributed gather into registers + histogram.
    uint2 rec0, rec1, rec2, rec3;
    int lr0 = -1, lr1 = -1, lr2 = -1, lr3 = -1;
#define GATHER(I, RC, LR)                                                     \
    {                                                                         \
        const int m = tid + I * 256;                                          \
        if (m < cnt) {                                                        \
            int lo = 0, hi = 245;                                             \
            while (hi - lo > 1) {                                             \
                const int mid = (lo + hi) >> 1;                               \
                if (dbase[mid] <= m) lo = mid; else hi = mid;                 \
            }                                                                 \
            RC = srec[(size_t)lo * SC_EDGES + sst[lo] + (m - dbase[lo])];     \
            LR = (int)(RC.x >> 24);                                           \
            RC.x &= 0x00FFFFFFu;                                              \
            atomicAdd(&hist[LR], 1);                                          \
        }                                                                     \
    }
    GATHER(0, rec0, lr0)
    GATHER(1, rec1, lr1)
    GATHER(2, rec2, lr2)
    GATHER(3, rec3, lr3)
#undef GATHER
    __syncthreads();

    // Phase 2: single-wave padded scan over 64 rows.
    if (tid < 64) {
        const int c = hist[tid];
        const int p = (c + 3) & ~3;
        int sc = p;
#pragma unroll
        for (int off = 1; off < 64; off <<= 1) {
            int u = __shfl_up(sc, off);
            if (lane >= off) sc += u;
        }
        const int excl = sc - p;
        rst[tid] = excl;
        cur[tid] = excl;
        uint2 z; z.x = 0; z.y = 0;
        for (int i = c; i < p; ++i) lrecs[excl + i] = z;
        if (tid == 63) {
            rst[64] = excl + p;
            for (int i = 0; i < 16; ++i) lrecs[excl + p + i] = z;
        }
    }
    __syncthreads();

    // Phase 3: place held records (counting-sort into LDS).
    if (lr0 >= 0) lrecs[atomicAdd(&cur[lr0], 1)] = rec0;
    if (lr1 >= 0) lrecs[atomicAdd(&cur[lr1], 1)] = rec1;
    if (lr2 >= 0) lrecs[atomicAdd(&cur[lr2], 1)] = rec2;
    if (lr3 >= 0) lrecs[atomicAdd(&cur[lr3], 1)] = rec3;
    __syncthreads();

    // Phase 4: aggregation. Wave wv handles local rows wv, wv+4, ..., wv+60.
    const int j = lane & 15;
    const int sl = lane >> 4;
    const float4 t0 = ltab[j], t1 = ltab[j + 16], t2 = ltab[j + 32], t3 = ltab[j + 48];
    const float b2L = att_b2[0] * L2E;
    const float gg = ln_g[lane], bb = ln_b[lane];
    const unsigned* xvu = (const unsigned*)xv;

#pragma unroll 1
    for (int k = 0; k < 16; ++k) {
        const int lrw = wv + 4 * k;
        const int r = b * 64 + lrw;
        if (r >= N_NODES) break;

        const uint2 uu = *(const uint2*)(u_bf + (size_t)r * 64 + j * 4);
        const float base0 = __uint_as_float(uu.x << 16) + t0.z;
        const float base1 = __uint_as_float(uu.x & 0xffff0000u) + t1.z;
        const float base2 = __uint_as_float(uu.y << 16) + t2.z;
        const float base3 = __uint_as_float(uu.y & 0xffff0000u) + t3.z;

        const int s0 = rst[lrw];
        const int e1 = rst[lrw + 1];

        float a0 = 0.f, a1 = 0.f, a2 = 0.f, a3 = 0.f;
        if (e1 > s0) {
            uint2 recA = lrecs[s0 + sl];
            uint2 recB = lrecs[s0 + 4 + sl];
            uint4 xvA = *(const uint4*)(xvu + (size_t)recA.x * 64 + j * 4);
            uint4 xvB = *(const uint4*)(xvu + (size_t)recB.x * 64 + j * 4);
            for (int e = s0; e < e1; e += 4) {
                const uint2 recC = lrecs[e + 8 + sl];
                const uint4 xvC = *(const uint4*)(xvu + (size_t)recC.x * 64 + j * 4);

                const float dst = __uint_as_float(recA.y << 16);
                const float emN = __uint_as_float(recA.y & 0xffff0000u);
                const float x0 = __uint_as_float(xvA.x << 16);
                const float x1 = __uint_as_float(xvA.x & 0xffff0000u);
                const float x2 = __uint_as_float(xvA.y << 16);
                const float x3 = __uint_as_float(xvA.y & 0xffff0000u);
                const float v0 = __uint_as_float(xvA.z << 16);
                const float v1 = __uint_as_float(xvA.z & 0xffff0000u);
                const float v2 = __uint_as_float(xvA.w << 16);
                const float v3 = __uint_as_float(xvA.w & 0xffff0000u);
                float pv = 0.f, pre, sg;
                pre = fmaf(dst, t0.y, base0) + v0;
                sg = __builtin_amdgcn_rcpf(1.f + __builtin_amdgcn_exp2f(-pre));
                pv = fmaf(pre * sg, t0.x, pv);
                pre = fmaf(dst, t1.y, base1) + v1;
                sg = __builtin_amdgcn_rcpf(1.f + __builtin_amdgcn_exp2f(-pre));
                pv = fmaf(pre * sg, t1.x, pv);
                pre = fmaf(dst, t2.y, base2) + v2;
                sg = __builtin_amdgcn_rcpf(1.f + __builtin_amdgcn_exp2f(-pre));
                pv = fmaf(pre * sg, t2.x, pv);
                pre = fmaf(dst, t3.y, base3) + v3;
                sg = __builtin_amdgcn_rcpf(1.f + __builtin_amdgcn_exp2f(-pre));
                pv = fmaf(pre * sg, t3.x, pv);
                pv += __shfl_xor(pv, 1); pv += __shfl_xor(pv, 2);
                pv += __shfl_xor(pv, 4); pv += __shfl_xor(pv, 8);
                const float sp = fmaf(pv, L2E, b2L);
                const float att =
                    emN * __builtin_amdgcn_rcpf(1.f + __builtin_amdgcn_exp2f(-sp));
                a0 = fmaf(att, x0, a0); a1 = fmaf(att, x1, a1);
                a2 = fmaf(att, x2, a2); a3 = fmaf(att, x3, a3);
                recA = recB; xvA = xvB; recB = recC; xvB = xvC;
            }
        }
        a0 += __shfl_xor(a0, 16); a0 += __shfl_xor(a0, 32);
        a1 += __shfl_xor(a1, 16); a1 += __shfl_xor(a1, 32);
        a2 += __shfl_xor(a2, 16); a2 += __shfl_xor(a2, 32);
        a3 += __shfl_xor(a3, 16); a3 += __shfl_xor(a3, 32);

        const uint2 xr = *(const uint2*)(xvu + (size_t)r * 64 + j * 4);
        const float o0 = __uint_as_float(xr.x << 16) + a0;
        const float o1 = __uint_as_float(xr.x & 0xffff0000u) + a1;
        const float o2 = __uint_as_float(xr.y << 16) + a2;
        const float o3 = __uint_as_float(xr.y & 0xffff0000u) + a3;

        float ssum = o0 + o1 + o2 + o3;
        ssum += __shfl_xor(ssum, 1); ssum += __shfl_xor(ssum, 2);
        ssum += __shfl_xor(ssum, 4); ssum += __shfl_xor(ssum, 8);
        const float mu = ssum * (1.f / 64.f);
        const float d0 = o0 - mu, d1 = o1 - mu, d2 = o2 - mu, d3 = o3 - mu;
        float vs = d0 * d0 + d1 * d1 + d2 * d2 + d3 * d3;
        vs += __shfl_xor(vs, 1); vs += __shfl_xor(vs, 2);
        vs += __shfl_xor(vs, 4); vs += __shfl_xor(vs, 8);
        const float rstd = rsqrtf(vs * (1.f / 64.f) + LN_EPS);

        const float dk = (sl == 0) ? d0 : (sl == 1) ? d1 : (sl == 2) ? d2 : d3;
        const float y = fmaf(dk * rstd, gg, bb);
        out[(size_t)r * 64 + lane] =
            y * __builtin_amdgcn_rcpf(1.f + __builtin_amdgcn_exp2f(-y * L2E));
    }
}

extern "C" void kernel_launch(void* const* d_in, const int* in_sizes, int n_in,
                              void* d_out, int out_size, void* d_ws, size_t ws_size,
                              hipStream_t stream) {
    const float* h      = (const float*)d_in[0];
    const float* dist   = (const float*)d_in[1];
    const int*   edges  = (const int*)d_in[2];
    const float* emask  = (const float*)d_in[4];
    const float* W_lin  = (const float*)d_in[5];
    const float* b_lin  = (const float*)d_in[6];
    const float* att_W1 = (const float*)d_in[7];
    const float* att_b1 = (const float*)d_in[8];
    const float* att_W2 = (const float*)d_in[9];
    const float* att_b2 = (const float*)d_in[10];
    const float* ln_g   = (const float*)d_in[11];
    const float* ln_b   = (const float*)d_in[12];
    float* out = (float*)d_out;

    char* ws = (char*)d_ws;
    unsigned short* xv   = (unsigned short*)ws;                  // 25,600,000
    unsigned short* u_bf = (unsigned short*)(ws + 25600000);     // 12,800,000
    uint2* srec          = (uint2*)(ws + 38400000);              //  8,028,160 (245*4096*8)
    unsigned short* ofsT = (unsigned short*)(ws + 46428160);     //    768,320 (245*1568*2)

    proj_scatter<<<SC_BLOCKS + PROJ_BLOCKS, 256, 0, stream>>>(
        h, b_lin, W_lin, att_W1, edges, dist, emask, srec, ofsT, xv, u_bf);
    agg_fused<<<AGG_C0, 256, 0, stream>>>(srec, ofsT, xv, u_bf,
                                          att_W1, att_b1, att_W2, att_b2,
                                          ln_g, ln_b, out, 0);
    agg_fused<<<AGG_C1, 256, 0, stream>>>(srec, ofsT, xv, u_bf,
                                          att_W1, att_b1, att_W2, att_b2,
                                          ln_g, ln_b, out, AGG_C0);
}

// Round 12
// 191.175 us; speedup vs baseline: 1.2195x; 1.2195x over previous
//
#include <hip/hip_runtime.h>
#include <hip/hip_bf16.h>

#define N_NODES 100000
#define N_EDGES 1000000
#define DIM 64
#define NORM_INV 0.01f
#define LN_EPS 1e-5f
#define N_TILES 6250          // N_NODES/16
#define PROJ_BLOCKS 1563      // ceil(6250/4)
#define N_BUCKETS 1563        // ceil(100000/64), 64 rows per bucket
#define HB_PK 784             // packed-int count: 1568 u16 bins (>=1564)
#define SC_EDGES 4096         // edges per scatter slice
#define SC_BLOCKS 245         // ceil(1e6/4096)
#define OFS_COL 256           // u16 per ofsT column (245 used, padded)
#define L2E 1.4426950408889634f
#define LN2 0.6931471805599453f
#define CAP 1280              // LDS record capacity/bucket

typedef __attribute__((ext_vector_type(8))) short short8;
typedef __attribute__((ext_vector_type(4))) float f32x4;

__device__ __forceinline__ unsigned short f2bf(float f) {
    union { float f; unsigned u; } x; x.f = f;
    unsigned r = x.u + 0x7FFFu + ((x.u >> 16) & 1u);
    return (unsigned short)(r >> 16);
}
__device__ __forceinline__ float bf2f(unsigned short s) {
    union { unsigned u; float f; } x; x.u = ((unsigned)s) << 16; return x.f;
}

// ---------------------------------------------------------------------------
// proj_scatter fat kernel (round-8 structure + round-9 uint4 fused xv store).
// blocks [0, SC_BLOCKS): fixed-slice scatter. 1563 bins (64-row buckets),
//   two 16-bit counters packed per LDS int. srec.x = col | lrow<<24.
//   ofsT written TRANSPOSED (bucket-major, u16): ofsT[b*256 + slice] —
//   agg's phase-0 column read becomes two coalesced 512-B loads instead of
//   245 strided cache-line touches per block.
// blocks [SC_BLOCKS, +PROJ_BLOCKS): MFMA projection, 1 tile/wave; weight
//   fragments built in-block into LDS (32 KB), whi/wlo region reused for lw.
// ---------------------------------------------------------------------------
__global__ __launch_bounds__(256) void proj_scatter(
    const float* __restrict__ h, const float* __restrict__ bl,
    const float* __restrict__ W, const float* __restrict__ att_W1,
    const int* __restrict__ edges, const float* __restrict__ dist,
    const float* __restrict__ emask,
    uint2* __restrict__ srec, unsigned short* __restrict__ ofsT,
    unsigned short* __restrict__ xv, unsigned short* __restrict__ u_bf) {
    __shared__ __align__(16) char pool[39168];
    __shared__ int wsum[4];

    if (blockIdx.x < SC_BLOCKS) {
        // ------------------- scatter personality -------------------
        int* lh = (int*)pool;                       // [HB_PK] packed counts
        int* lofsP = (int*)pool + HB_PK;            // [HB_PK] packed offsets
        uint2* lsort = (uint2*)(pool + 6272);       // [SC_EDGES]
        const int blk = blockIdx.x;
        const int tid = threadIdx.x;
        const int lane = tid & 63;
        const int w = tid >> 6;
        for (int i = tid; i < HB_PK; i += 256) lh[i] = 0;
        __syncthreads();

        const int eb = blk * SC_EDGES;
        const int total = min(SC_EDGES, N_EDGES - eb);

        // Phase A: load 16 edges/thread, histogram with rank capture.
        int rows[16], rank[16];
        uint2 recs[16];
        const int e0 = eb + tid * 16;
#pragma unroll
        for (int g = 0; g < 4; ++g) {
            const int e = e0 + g * 4;
            if (e + 4 <= N_EDGES) {
                const int4 rr = *(const int4*)(edges + e);
                const int4 cc = *(const int4*)(edges + N_EDGES + e);
                const float4 dd = *(const float4*)(dist + e);
                const float4 mm = *(const float4*)(emask + e);
                rows[g*4+0] = rr.x; rows[g*4+1] = rr.y; rows[g*4+2] = rr.z; rows[g*4+3] = rr.w;
                const int c4[4] = {cc.x, cc.y, cc.z, cc.w};
                const float d4[4] = {dd.x, dd.y, dd.z, dd.w};
                const float m4[4] = {mm.x, mm.y, mm.z, mm.w};
#pragma unroll
                for (int i = 0; i < 4; ++i) {
                    const int ii = g * 4 + i;
                    recs[ii].x = (unsigned)c4[i] | ((unsigned)(rows[ii] & 63) << 24);
                    recs[ii].y = (unsigned)f2bf(d4[i]) |
                                 ((unsigned)f2bf(m4[i] * NORM_INV) << 16);
                    const int bk = rows[ii] >> 6;
                    const int sh = (bk & 1) << 4;
                    rank[ii] = (atomicAdd(&lh[bk >> 1], 1 << sh) >> sh) & 0xffff;
                }
            } else {
#pragma unroll
                for (int i = 0; i < 4; ++i) {
                    const int ii = g * 4 + i;
                    const int ee = e + i;
                    if (ee < N_EDGES) {
                        rows[ii] = edges[ee];
                        recs[ii].x = (unsigned)edges[N_EDGES + ee] |
                                     ((unsigned)(rows[ii] & 63) << 24);
                        recs[ii].y = (unsigned)f2bf(dist[ee]) |
                                     ((unsigned)f2bf(emask[ee] * NORM_INV) << 16);
                        const int bk = rows[ii] >> 6;
                        const int sh = (bk & 1) << 4;
                        rank[ii] = (atomicAdd(&lh[bk >> 1], 1 << sh) >> sh) & 0xffff;
                    } else {
                        rows[ii] = -1;
                    }
                }
            }
        }
        __syncthreads();

        // Phase B: 8-bins/thread exclusive scan over 1568 packed bins.
        const int t4 = tid * 4;
        int li[4];
#pragma unroll
        for (int g = 0; g < 4; ++g) li[g] = (t4 + g < HB_PK) ? lh[t4 + g] : 0;
        int cs[8];
#pragma unroll
        for (int g = 0; g < 4; ++g) {
            cs[2*g]   = li[g] & 0xffff;
            cs[2*g+1] = (li[g] >> 16) & 0xffff;
        }
        int S = 0;
#pragma unroll
        for (int k = 0; k < 8; ++k) S += cs[k];
        int sc = S;
#pragma unroll
        for (int off = 1; off < 64; off <<= 1) {
            int u = __shfl_up(sc, off);
            if (lane >= off) sc += u;
        }
        if (lane == 63) wsum[w] = sc;
        __syncthreads();
        int wbase = 0;
        if (w > 0) wbase = wsum[0];
        if (w > 1) wbase += wsum[1];
        if (w > 2) wbase += wsum[2];
        int run = sc - S + wbase;
#pragma unroll
        for (int g = 0; g < 4; ++g) {
            const int lo = run; run += cs[2*g];
            const int hi = run; run += cs[2*g+1];
            if (t4 + g < HB_PK) lofsP[t4 + g] = (unsigned)lo | ((unsigned)hi << 16);
        }
        __syncthreads();

        // Phase C: place into LDS sorted by bucket.
#pragma unroll
        for (int i = 0; i < 16; ++i) {
            if (rows[i] >= 0) {
                const int bk = rows[i] >> 6;
                const int base = (lofsP[bk >> 1] >> ((bk & 1) << 4)) & 0xffff;
                lsort[base + rank[i]] = recs[i];
            }
        }
        __syncthreads();

        // Phase D: coalesced slice write-out + TRANSPOSED u16 ofsT column.
        for (int s = tid; s < total; s += 256)
            srec[(size_t)blk * SC_EDGES + s] = lsort[s];
        for (int b = tid; b < 1564; b += 256)
            ofsT[(size_t)b * OFS_COL + blk] =
                (unsigned short)((lofsP[b >> 1] >> ((b & 1) << 4)) & 0xffff);
        return;
    }

    // ------------------- projection personality -------------------
    const int tid = threadIdx.x;
    const int lane = tid & 63;
    const int wv = tid >> 6;
    const int c = lane & 15, q = lane >> 4;

    // In-block fragment build: W hi/lo split + att_W1 a/b fragments -> LDS.
    {
        short8* Lwhi_w = (short8*)pool;
        short8* Lwlo_w = Lwhi_w + 512;
        short8* Lwa_w  = Lwhi_w + 1024;
        short8* Lwb_w  = Lwhi_w + 1536;
        const int nt_b = tid >> 6;
        const int n_b = nt_b * 16 + c;
#pragma unroll
        for (int ks = 0; ks < 2; ++ks) {
            const int k0 = ks * 32 + q * 8;
            short8 hi8, lo8, a8, b8;
#pragma unroll
            for (int jj = 0; jj < 8; ++jj) {
                float w = W[n_b * 64 + k0 + jj];
                unsigned short hh = f2bf(w);
                hi8[jj] = (short)hh;
                lo8[jj] = (short)f2bf(w - bf2f(hh));
                a8[jj] = (short)f2bf(att_W1[n_b * 129 + k0 + jj]);
                b8[jj] = (short)f2bf(att_W1[n_b * 129 + 64 + k0 + jj]);
            }
            const int idx = (nt_b * 2 + ks) * 64 + lane;
            Lwhi_w[idx] = hi8; Lwlo_w[idx] = lo8; Lwa_w[idx] = a8; Lwb_w[idx] = b8;
        }
    }
    __syncthreads();
    const short8* Lwhi = (const short8*)pool;
    const short8* Lwlo = Lwhi + 512;
    const short8* Lwa  = Lwhi + 1024;
    const short8* Lwb  = Lwhi + 1536;

    const int tile = (blockIdx.x - SC_BLOCKS) * 4 + wv;
    const bool valid = (tile < N_TILES);
    const int n0 = valid ? tile * 16 : 0;

    float bias[4];
#pragma unroll
    for (int nt = 0; nt < 4; ++nt) bias[nt] = bl[nt * 16 + c];

    short8 Ahi[2], Alo[2];
#pragma unroll
    for (int ks = 0; ks < 2; ++ks) {
        const float* hp = h + (size_t)(n0 + c) * 64 + ks * 32 + q * 8;
        f32x4 p0 = *(const f32x4*)hp;
        f32x4 p1 = *(const f32x4*)(hp + 4);
        short8 hi8, lo8;
#pragma unroll
        for (int jj = 0; jj < 4; ++jj) {
            unsigned short hh = f2bf(p0[jj]);
            hi8[jj] = (short)hh; lo8[jj] = (short)f2bf(p0[jj] - bf2f(hh));
            unsigned short h2 = f2bf(p1[jj]);
            hi8[4 + jj] = (short)h2; lo8[4 + jj] = (short)f2bf(p1[jj] - bf2f(h2));
        }
        Ahi[ks] = hi8; Alo[ks] = lo8;
    }

    f32x4 xacc[4] = {{0,0,0,0},{0,0,0,0},{0,0,0,0},{0,0,0,0}};
#pragma unroll
    for (int ks = 0; ks < 2; ++ks)
#pragma unroll
        for (int nt = 0; nt < 4; ++nt) {
            const short8 fhi = Lwhi[(nt * 2 + ks) * 64 + lane];
            const short8 flo = Lwlo[(nt * 2 + ks) * 64 + lane];
            xacc[nt] = __builtin_amdgcn_mfma_f32_16x16x32_bf16(Ahi[ks], fhi, xacc[nt], 0, 0, 0);
            xacc[nt] = __builtin_amdgcn_mfma_f32_16x16x32_bf16(Ahi[ks], flo, xacc[nt], 0, 0, 0);
            xacc[nt] = __builtin_amdgcn_mfma_f32_16x16x32_bf16(Alo[ks], fhi, xacc[nt], 0, 0, 0);
        }

    // whi/wlo fragments are dead from here; reuse [0:9216) of pool for lw.
    __syncthreads();

    unsigned short* lw = (unsigned short*)pool + wv * (16 * 72);
    uint2 xpk[4];                    // packed x per r, held until fused store
#pragma unroll
    for (int r = 0; r < 4; ++r) {
        unsigned short xb[4];
#pragma unroll
        for (int nt = 0; nt < 4; ++nt) {
            unsigned short v16 = f2bf(xacc[nt][r] + bias[nt]);
            xb[nt] = v16;
            lw[(q * 4 + r) * 72 + nt * 16 + c] = v16;
        }
        xpk[r].x = (unsigned)xb[0] | ((unsigned)xb[1] << 16);
        xpk[r].y = (unsigned)xb[2] | ((unsigned)xb[3] << 16);
    }

    short8 Ax[2];
#pragma unroll
    for (int ks = 0; ks < 2; ++ks)
        Ax[ks] = *(const short8*)&lw[c * 72 + ks * 32 + q * 8];

    f32x4 uacc[4] = {{0,0,0,0},{0,0,0,0},{0,0,0,0},{0,0,0,0}};
    f32x4 vacc[4] = {{0,0,0,0},{0,0,0,0},{0,0,0,0},{0,0,0,0}};
#pragma unroll
    for (int ks = 0; ks < 2; ++ks)
#pragma unroll
        for (int nt = 0; nt < 4; ++nt) {
            const short8 fa = Lwa[(nt * 2 + ks) * 64 + lane];
            const short8 fb = Lwb[(nt * 2 + ks) * 64 + lane];
            uacc[nt] = __builtin_amdgcn_mfma_f32_16x16x32_bf16(Ax[ks], fa, uacc[nt], 0, 0, 0);
            vacc[nt] = __builtin_amdgcn_mfma_f32_16x16x32_bf16(Ax[ks], fb, vacc[nt], 0, 0, 0);
        }
    if (valid) {
#pragma unroll
        for (int r = 0; r < 4; ++r) {
            const int node = n0 + q * 4 + r;
            uint2 pu;
            pu.x = (unsigned)f2bf(uacc[0][r] * L2E) | ((unsigned)f2bf(uacc[1][r] * L2E) << 16);
            pu.y = (unsigned)f2bf(uacc[2][r] * L2E) | ((unsigned)f2bf(uacc[3][r] * L2E) << 16);
            *(uint2*)(u_bf + (size_t)node * 64 + c * 4) = pu;
            uint4 pk;
            pk.x = xpk[r].x;
            pk.y = xpk[r].y;
            pk.z = (unsigned)f2bf(vacc[0][r] * L2E) | ((unsigned)f2bf(vacc[1][r] * L2E) << 16);
            pk.w = (unsigned)f2bf(vacc[2][r] * L2E) | ((unsigned)f2bf(vacc[3][r] * L2E) << 16);
            *(uint4*)(xv + (size_t)node * 128 + c * 8) = pk;
        }
    }
}

// ---------------------------------------------------------------------------
// agg_fused: one block (256 thr, 4 waves) per 64-row bucket, single launch.
// Phase 0: TWO coalesced 512-B column loads from transposed ofsT -> dbase[].
// Phase 1: distributed gather into registers (<=4/thread) + LDS histogram.
// Phase 2: single-wave padded (x4) scan over 64 rows -> LDS row starts.
// Phase 3: place held records via cur atomics.
// Phase 4: 16 k-iterations/wave with NEXT-K PREFETCH of the u_bf/xv row
//          loads (fixed addresses): issued before the current k's e-loop so
//          their latency hides under ~1000 cycles of compute.
// ---------------------------------------------------------------------------
__global__ __launch_bounds__(256, 8) void agg_fused(
    const uint2* __restrict__ srec, const unsigned short* __restrict__ ofsT,
    const unsigned short* __restrict__ xv, const unsigned short* __restrict__ u_bf,
    const float* __restrict__ att_W1, const float* __restrict__ att_b1,
    const float* __restrict__ att_W2, const float* __restrict__ att_b2,
    const float* __restrict__ ln_g, const float* __restrict__ ln_b,
    float* __restrict__ out) {
    __shared__ __align__(16) uint2 lrecs[CAP + 16];
    __shared__ float4 ltab[64];
    __shared__ int hist[64];
    __shared__ int rst[65];
    __shared__ int cur[64];
    __shared__ int sst[256];
    __shared__ int dbase[257];
    __shared__ int wsum4[4];

    const int b = blockIdx.x;
    const int tid = threadIdx.x;
    const int lane = tid & 63;
    const int wv = tid >> 6;

    if (tid < 64) hist[tid] = 0;
    if (tid >= 192) {
        const int f = tid - 192;
        ltab[f] = make_float4(att_W2[f] * LN2, att_W1[f * 129 + 128] * L2E,
                              att_b1[f] * L2E, 0.f);
    }

    // Phase 0: coalesced column loads + exclusive scan over 256 threads.
    int stv = 0, len = 0, sc0 = 0;
    {
        if (tid < SC_BLOCKS) {
            stv = (int)ofsT[(size_t)b * OFS_COL + tid];
            len = (int)ofsT[(size_t)(b + 1) * OFS_COL + tid] - stv;
        }
        sst[tid] = stv;
        sc0 = len;
#pragma unroll
        for (int off = 1; off < 64; off <<= 1) {
            int u = __shfl_up(sc0, off);
            if (lane >= off) sc0 += u;
        }
        if (lane == 63) wsum4[wv] = sc0;
    }
    __syncthreads();
    {
        int wbase = 0;
        if (wv > 0) wbase = wsum4[0];
        if (wv > 1) wbase += wsum4[1];
        if (wv > 2) wbase += wsum4[2];
        dbase[tid] = wbase + sc0 - len;
        if (tid == 255) dbase[256] = wbase + sc0;
    }
    __syncthreads();
    const int cnt = dbase[245];

    // Phase 1: distributed gather into registers + histogram.
    uint2 rec0, rec1, rec2, rec3;
    int lr0 = -1, lr1 = -1, lr2 = -1, lr3 = -1;
#define GATHER(I, RC, LR)                                                     \
    {                                                                         \
        const int m = tid + I * 256;                                          \
        if (m < cnt) {                                                        \
            int lo = 0, hi = 245;                                             \
            while (hi - lo > 1) {                                             \
                const int mid = (lo + hi) >> 1;                               \
                if (dbase[mid] <= m) lo = mid; else hi = mid;                 \
            }                                                                 \
            RC = srec[(size_t)lo * SC_EDGES + sst[lo] + (m - dbase[lo])];     \
            LR = (int)(RC.x >> 24);                                           \
            RC.x &= 0x00FFFFFFu;                                              \
            atomicAdd(&hist[LR], 1);                                          \
        }                                                                     \
    }
    GATHER(0, rec0, lr0)
    GATHER(1, rec1, lr1)
    GATHER(2, rec2, lr2)
    GATHER(3, rec3, lr3)
#undef GATHER
    __syncthreads();

    // Phase 2: single-wave padded scan over 64 rows.
    if (tid < 64) {
        const int c = hist[tid];
        const int p = (c + 3) & ~3;
        int sc = p;
#pragma unroll
        for (int off = 1; off < 64; off <<= 1) {
            int u = __shfl_up(sc, off);
            if (lane >= off) sc += u;
        }
        const int excl = sc - p;
        rst[tid] = excl;
        cur[tid] = excl;
        uint2 z; z.x = 0; z.y = 0;
        for (int i = c; i < p; ++i) lrecs[excl + i] = z;
        if (tid == 63) {
            rst[64] = excl + p;
            for (int i = 0; i < 16; ++i) lrecs[excl + p + i] = z;
        }
    }
    __syncthreads();

    // Phase 3: place held records (counting-sort into LDS).
    if (lr0 >= 0) lrecs[atomicAdd(&cur[lr0], 1)] = rec0;
    if (lr1 >= 0) lrecs[atomicAdd(&cur[lr1], 1)] = rec1;
    if (lr2 >= 0) lrecs[atomicAdd(&cur[lr2], 1)] = rec2;
    if (lr3 >= 0) lrecs[atomicAdd(&cur[lr3], 1)] = rec3;
    __syncthreads();

    // Phase 4: aggregation with next-k prefetch.
    const int j = lane & 15;
    const int sl = lane >> 4;
    const float4 t0 = ltab[j], t1 = ltab[j + 16], t2 = ltab[j + 32], t3 = ltab[j + 48];
    const float b2L = att_b2[0] * L2E;
    const float gg = ln_g[lane], bb = ln_b[lane];
    const unsigned* xvu = (const unsigned*)xv;

    int r = b * 64 + wv;
    uint2 uu, xr;
    if (r < N_NODES) {
        uu = *(const uint2*)(u_bf + (size_t)r * 64 + j * 4);
        xr = *(const uint2*)(xvu + (size_t)r * 64 + j * 4);
    }

#pragma unroll 1
    for (int k = 0; k < 16; ++k) {
        const int lrw = wv + 4 * k;
        if (r >= N_NODES) break;

        // Prefetch next k's row data before this k's compute.
        const int rN = r + 4;
        uint2 uuN, xrN;
        const bool haveN = (k < 15) && (rN < N_NODES);
        if (haveN) {
            uuN = *(const uint2*)(u_bf + (size_t)rN * 64 + j * 4);
            xrN = *(const uint2*)(xvu + (size_t)rN * 64 + j * 4);
        }

        const float base0 = __uint_as_float(uu.x << 16) + t0.z;
        const float base1 = __uint_as_float(uu.x & 0xffff0000u) + t1.z;
        const float base2 = __uint_as_float(uu.y << 16) + t2.z;
        const float base3 = __uint_as_float(uu.y & 0xffff0000u) + t3.z;

        const int s0 = rst[lrw];
        const int e1 = rst[lrw + 1];

        float a0 = 0.f, a1 = 0.f, a2 = 0.f, a3 = 0.f;
        if (e1 > s0) {
            uint2 recA = lrecs[s0 + sl];
            uint2 recB = lrecs[s0 + 4 + sl];
            uint4 xvA = *(const uint4*)(xvu + (size_t)recA.x * 64 + j * 4);
            uint4 xvB = *(const uint4*)(xvu + (size_t)recB.x * 64 + j * 4);
            for (int e = s0; e < e1; e += 4) {
                const uint2 recC = lrecs[e + 8 + sl];
                const uint4 xvC = *(const uint4*)(xvu + (size_t)recC.x * 64 + j * 4);

                const float dst = __uint_as_float(recA.y << 16);
                const float emN = __uint_as_float(recA.y & 0xffff0000u);
                const float x0 = __uint_as_float(xvA.x << 16);
                const float x1 = __uint_as_float(xvA.x & 0xffff0000u);
                const float x2 = __uint_as_float(xvA.y << 16);
                const float x3 = __uint_as_float(xvA.y & 0xffff0000u);
                const float v0 = __uint_as_float(xvA.z << 16);
                const float v1 = __uint_as_float(xvA.z & 0xffff0000u);
                const float v2 = __uint_as_float(xvA.w << 16);
                const float v3 = __uint_as_float(xvA.w & 0xffff0000u);
                float pv = 0.f, pre, sg;
                pre = fmaf(dst, t0.y, base0) + v0;
                sg = __builtin_amdgcn_rcpf(1.f + __builtin_amdgcn_exp2f(-pre));
                pv = fmaf(pre * sg, t0.x, pv);
                pre = fmaf(dst, t1.y, base1) + v1;
                sg = __builtin_amdgcn_rcpf(1.f + __builtin_amdgcn_exp2f(-pre));
                pv = fmaf(pre * sg, t1.x, pv);
                pre = fmaf(dst, t2.y, base2) + v2;
                sg = __builtin_amdgcn_rcpf(1.f + __builtin_amdgcn_exp2f(-pre));
                pv = fmaf(pre * sg, t2.x, pv);
                pre = fmaf(dst, t3.y, base3) + v3;
                sg = __builtin_amdgcn_rcpf(1.f + __builtin_amdgcn_exp2f(-pre));
                pv = fmaf(pre * sg, t3.x, pv);
                pv += __shfl_xor(pv, 1); pv += __shfl_xor(pv, 2);
                pv += __shfl_xor(pv, 4); pv += __shfl_xor(pv, 8);
                const float sp = fmaf(pv, L2E, b2L);
                const float att =
                    emN * __builtin_amdgcn_rcpf(1.f + __builtin_amdgcn_exp2f(-sp));
                a0 = fmaf(att, x0, a0); a1 = fmaf(att, x1, a1);
                a2 = fmaf(att, x2, a2); a3 = fmaf(att, x3, a3);
                recA = recB; xvA = xvB; recB = recC; xvB = xvC;
            }
        }
        a0 += __shfl_xor(a0, 16); a0 += __shfl_xor(a0, 32);
        a1 += __shfl_xor(a1, 16); a1 += __shfl_xor(a1, 32);
        a2 += __shfl_xor(a2, 16); a2 += __shfl_xor(a2, 32);
        a3 += __shfl_xor(a3, 16); a3 += __shfl_xor(a3, 32);

        const float o0 = __uint_as_float(xr.x << 16) + a0;
        const float o1 = __uint_as_float(xr.x & 0xffff0000u) + a1;
        const float o2 = __uint_as_float(xr.y << 16) + a2;
        const float o3 = __uint_as_float(xr.y & 0xffff0000u) + a3;

        float ssum = o0 + o1 + o2 + o3;
        ssum += __shfl_xor(ssum, 1); ssum += __shfl_xor(ssum, 2);
        ssum += __shfl_xor(ssum, 4); ssum += __shfl_xor(ssum, 8);
        const float mu = ssum * (1.f / 64.f);
        const float d0 = o0 - mu, d1 = o1 - mu, d2 = o2 - mu, d3 = o3 - mu;
        float vs = d0 * d0 + d1 * d1 + d2 * d2 + d3 * d3;
        vs += __shfl_xor(vs, 1); vs += __shfl_xor(vs, 2);
        vs += __shfl_xor(vs, 4); vs += __shfl_xor(vs, 8);
        const float rstd = rsqrtf(vs * (1.f / 64.f) + LN_EPS);

        const float dk = (sl == 0) ? d0 : (sl == 1) ? d1 : (sl == 2) ? d2 : d3;
        const float y = fmaf(dk * rstd, gg, bb);
        out[(size_t)r * 64 + lane] =
            y * __builtin_amdgcn_rcpf(1.f + __builtin_amdgcn_exp2f(-y * L2E));

        uu = uuN; xr = xrN; r = rN;
    }
}

extern "C" void kernel_launch(void* const* d_in, const int* in_sizes, int n_in,
                              void* d_out, int out_size, void* d_ws, size_t ws_size,
                              hipStream_t stream) {
    const float* h      = (const float*)d_in[0];
    const float* dist   = (const float*)d_in[1];
    const int*   edges  = (const int*)d_in[2];
    const float* emask  = (const float*)d_in[4];
    const float* W_lin  = (const float*)d_in[5];
    const float* b_lin  = (const float*)d_in[6];
    const float* att_W1 = (const float*)d_in[7];
    const float* att_b1 = (const float*)d_in[8];
    const float* att_W2 = (const float*)d_in[9];
    const float* att_b2 = (const float*)d_in[10];
    const float* ln_g   = (const float*)d_in[11];
    const float* ln_b   = (const float*)d_in[12];
    float* out = (float*)d_out;

    char* ws = (char*)d_ws;
    unsigned short* xv   = (unsigned short*)ws;                  // 25,600,000
    unsigned short* u_bf = (unsigned short*)(ws + 25600000);     // 12,800,000
    uint2* srec          = (uint2*)(ws + 38400000);              //  8,028,160 (245*4096*8)
    unsigned short* ofsT = (unsigned short*)(ws + 46428160);     //    800,768 (1564*256*2)

    proj_scatter<<<SC_BLOCKS + PROJ_BLOCKS, 256, 0, stream>>>(
        h, b_lin, W_lin, att_W1, edges, dist, emask, srec, ofsT, xv, u_bf);
    agg_fused<<<N_BUCKETS, 256, 0, stream>>>(srec, ofsT, xv, u_bf,
                                             att_W1, att_b1, att_W2, att_b2,
                                             ln_g, ln_b, out);
}